// Round 4
// baseline (166.251 us; speedup 1.0000x reference)
//
#include <hip/hip_runtime.h>
#include <hip/hip_bf16.h>
#include <cstdint>
#include <cstddef>

// Problem constants (B,S,D,F,E,K) = (2,2048,1024,1024,8,2)
#define T_TOK 4096
#define DDIM  1024
#define FDIM  1024
#define NEXP  8

typedef __attribute__((ext_vector_type(8))) short bf16x8;
typedef __attribute__((ext_vector_type(4))) float f32x4;
typedef __attribute__((ext_vector_type(8))) unsigned short u16x8;

__device__ __forceinline__ unsigned short f2bf(float f) {
  unsigned int u = __float_as_uint(f);
  u += 0x7FFFu + ((u >> 16) & 1u);   // RNE
  return (unsigned short)(u >> 16);
}
__device__ __forceinline__ float bf2f(unsigned short u) {
  return __uint_as_float(((unsigned int)u) << 16);
}

__device__ __forceinline__ void gload_lds16(const void* g, void* l) {
  __builtin_amdgcn_global_load_lds(
      (const __attribute__((address_space(1))) unsigned int*)g,
      (__attribute__((address_space(3))) unsigned int*)l, 16, 0, 0);
}

// raw sync primitives (gemm2's counted pipeline)
__device__ __forceinline__ void vwait6() { asm volatile("s_waitcnt vmcnt(6)" ::: "memory"); }
__device__ __forceinline__ void vwait0() { asm volatile("s_waitcnt vmcnt(0)" ::: "memory"); }
__device__ __forceinline__ void lwait0() { asm volatile("s_waitcnt lgkmcnt(0)" ::: "memory"); }
__device__ __forceinline__ void barr()   { asm volatile("s_barrier" ::: "memory"); }

// swizzled fragment read: tile rows are 64 bf16 = 128B; byte ^= ((row&7)<<4)
// matches the pre-swizzled global source in the staging loops (rule #21).
__device__ __forceinline__ bf16x8 frag_ld(const unsigned short* tile, int row, int kk) {
  int byteoff = (row << 7) + ((kk * 2) ^ ((row & 7) << 4));
  return *reinterpret_cast<const bf16x8*>(reinterpret_cast<const char*>(tile) + byteoff);
}

// ---------------- prep: w1/w3 fp32->bf16 (blocks 0..2047) + gate (blocks 2048..3071) ----
// w2 conversion lives in gemm1's dispatch (rides in gemm1's HBM-BW shadow).
__global__ __launch_bounds__(256) void prep_kernel(
    const float* __restrict__ w1, const float* __restrict__ w3,
    unsigned short* __restrict__ W1b, unsigned short* __restrict__ W3b,
    const float* __restrict__ x, const float* __restrict__ gw,
    unsigned int* __restrict__ Xb32, int* __restrict__ tkidx, float* __restrict__ tkw,
    int* __restrict__ curp) {
  __shared__ float gws[NEXP * DDIM];   // 32 KB (gate blocks only)
  const int bid = blockIdx.x;
  const int tid = threadIdx.x;

  if (bid < 2048) {
    // ---- weight conversion: 1024 blocks per matrix (w1, w3) ----
    const int sub = bid >> 10;
    const int b = bid & 1023;
    const float* s = (sub == 0) ? w1 : w3;
    unsigned short* d = (sub == 0) ? W1b : W3b;
    const int n = NEXP * FDIM * DDIM;
    const int stride = 1024 * 256 * 8;
    for (int i = (b * 256 + tid) * 8; i < n; i += stride) {
      float4 a = *reinterpret_cast<const float4*>(s + i);
      float4 c = *reinterpret_cast<const float4*>(s + i + 4);
      u16x8 o;
      o[0] = f2bf(a.x); o[1] = f2bf(a.y); o[2] = f2bf(a.z); o[3] = f2bf(a.w);
      o[4] = f2bf(c.x); o[5] = f2bf(c.y); o[6] = f2bf(c.z); o[7] = f2bf(c.w);
      *reinterpret_cast<u16x8*>(d + i) = o;
    }
    return;
  }

  // ---- gate: 1024 blocks, 1 token per wave ----
  const int lane = tid & 63;
  const int wid = tid >> 6;
  if (bid == 2048 && tid < NEXP) curp[tid * 32] = 0;   // zero padded cursors for fill
  for (int i = tid; i < NEXP * DDIM / 4; i += 256)
    reinterpret_cast<float4*>(gws)[i] = reinterpret_cast<const float4*>(gw)[i];
  __syncthreads();

  const int t = (bid - 2048) * 4 + wid;
  const float2* xr = reinterpret_cast<const float2*>(x + (size_t)t * DDIM);
  float2 xv[8];
#pragma unroll
  for (int i = 0; i < 8; ++i) xv[i] = xr[i * 64 + lane];
  // fused x -> bf16 (packed pair store, coalesced 4B/lane)
#pragma unroll
  for (int i = 0; i < 8; ++i)
    Xb32[(size_t)t * 512 + i * 64 + lane] =
        (unsigned int)f2bf(xv[i].x) | ((unsigned int)f2bf(xv[i].y) << 16);
  float p[NEXP];
#pragma unroll
  for (int e = 0; e < NEXP; ++e) p[e] = 0.f;
#pragma unroll
  for (int i = 0; i < 8; ++i) {
    const int k = (i * 64 + lane) * 2;
#pragma unroll
    for (int e = 0; e < NEXP; ++e)
      p[e] += xv[i].x * gws[e * DDIM + k] + xv[i].y * gws[e * DDIM + k + 1];
  }
#pragma unroll
  for (int s = 32; s > 0; s >>= 1)
#pragma unroll
    for (int e = 0; e < NEXP; ++e) p[e] += __shfl_xor(p[e], s, 64);
  if (lane == 0) {
    int i0 = 0; float l0 = p[0];
#pragma unroll
    for (int e = 1; e < NEXP; ++e) if (p[e] > l0) { l0 = p[e]; i0 = e; }
    int i1 = -1; float l1 = -1e30f;
#pragma unroll
    for (int e = 0; e < NEXP; ++e) if (e != i0 && p[e] > l1) { l1 = p[e]; i1 = e; }
    float ex = __expf(l1 - l0);            // <= 1
    float w0 = 1.f / (1.f + ex);
    float w1v = ex / (1.f + ex);
    tkidx[t * 2] = i0; tkidx[t * 2 + 1] = i1;
    tkw[t * 2] = w0;   tkw[t * 2 + 1] = w1v;
  }
}

// ---------------- fill: global hist + off + compaction + compact work list ----------------
__global__ __launch_bounds__(256) void fill_kernel(const int* __restrict__ tkidx,
                                                   const float* __restrict__ tkw,
                                                   int* __restrict__ offp,
                                                   int* __restrict__ curp,
                                                   int* __restrict__ list,
                                                   float* __restrict__ rgate,
                                                   int* __restrict__ wmap,
                                                   int* __restrict__ nwp) {
  __shared__ int ghist[4][NEXP];
  __shared__ int lhist[NEXP], base[NEXP];
  const int tid = threadIdx.x;
  if (tid < 32) ghist[tid >> 3][tid & 7] = 0;
  if (tid < NEXP) lhist[tid] = 0;
  __syncthreads();
  for (int i = tid; i < 2 * T_TOK; i += 256)
    atomicAdd(&ghist[tid >> 6][tkidx[i]], 1);
  const int t = blockIdx.x * 256 + tid;
  const int e0 = tkidx[t * 2], e1 = tkidx[t * 2 + 1];
  const int r0 = atomicAdd(&lhist[e0], 1);
  const int r1 = atomicAdd(&lhist[e1], 1);
  __syncthreads();
  if (blockIdx.x == 0 && tid == 64) {
    // build compact (expert, rowtile) work list
    int nw = 0;
    for (int e = 0; e < NEXP; ++e) {
      int c = ghist[0][e] + ghist[1][e] + ghist[2][e] + ghist[3][e];
      int nrt = (c + 127) >> 7;
      for (int r = 0; r < nrt; ++r) wmap[nw++] = (e << 8) | r;
    }
    nwp[0] = nw;
  }
  if (tid < NEXP) {
    int o = 0;
#pragma unroll
    for (int j = 0; j < NEXP; ++j) {
      int c = ghist[0][j] + ghist[1][j] + ghist[2][j] + ghist[3][j];
      if (j < tid) o += c;
    }
    if (blockIdx.x == 0) {
      offp[tid] = o;
      if (tid == NEXP - 1)
        offp[NEXP] = o + ghist[0][tid] + ghist[1][tid] + ghist[2][tid] + ghist[3][tid];
    }
    base[tid] = o + atomicAdd(&curp[tid * 32], lhist[tid]);
  }
  __syncthreads();
  const int p0 = base[e0] + r0;
  const int p1 = base[e1] + r1;
  list[p0] = (t << 1);     rgate[p0] = tkw[t * 2];
  list[p1] = (t << 1) | 1; rgate[p1] = tkw[t * 2 + 1];
}

// ---------------- GEMM1: H = silu(X w1^T) * (X w3^T), gathered rows ----------------
// BM=128 tokens, BN=128 f-cols, BK=64. Single-buffered 48 KB LDS, 2-barrier
// m97-style schedule (the round-2 proven structure, fattened). 4 waves, each owns
// a 64x64 output for BOTH h1 and h3: per ks, 12 ds_read_b128 feed 32 MFMA
// (2.67:1 vs round-2's 1.33:1). ~210 VGPR -> 2 blocks/CU (LDS would allow 3).
// Blocks >= 72*8 convert w2 fp32->bf16 (rides in gemm1's HBM shadow).
__global__ __launch_bounds__(256) void gemm1_kernel(
    const unsigned short* __restrict__ Xb, const unsigned short* __restrict__ W1b,
    const unsigned short* __restrict__ W3b, unsigned short* __restrict__ Hb,
    const int* __restrict__ off, const int* __restrict__ list,
    const int* __restrict__ wmap, const int* __restrict__ nwp,
    const float* __restrict__ w2, unsigned short* __restrict__ W2b) {
  const int bid0 = blockIdx.x;
  const int tid = threadIdx.x;

  if (bid0 >= 72 * 8) {
    // ---- embedded w2 fp32->bf16 conversion (1024 blocks) ----
    const int b = bid0 - 72 * 8;
    const int n = NEXP * FDIM * DDIM;
    const int stride = 1024 * 256 * 8;
    for (int i = (b * 256 + tid) * 8; i < n; i += stride) {
      float4 a = *reinterpret_cast<const float4*>(w2 + i);
      float4 c = *reinterpret_cast<const float4*>(w2 + i + 4);
      u16x8 o;
      o[0] = f2bf(a.x); o[1] = f2bf(a.y); o[2] = f2bf(a.z); o[3] = f2bf(a.w);
      o[4] = f2bf(c.x); o[5] = f2bf(c.y); o[6] = f2bf(c.z); o[7] = f2bf(c.w);
      *reinterpret_cast<u16x8*>(W2b + i) = o;
    }
    return;
  }

  const int slot = bid0 >> 3;     // 72 rowtile slots
  const int ft = bid0 & 7;        // 8 f-col tiles of 128
  if (slot >= nwp[0]) return;
  const int ent = wmap[slot];
  const int e = ent >> 8;
  const int rt = ent & 255;
  const int seg0 = off[e];
  const int Ne = off[e + 1] - seg0;
  const int rowbase = rt * 128;   // < Ne by wmap construction
  const int f0 = ft * 128;

  __shared__ unsigned short As[128 * 64];    // 16 KB
  __shared__ unsigned short B1s[128 * 64];   // 16 KB
  __shared__ unsigned short B3s[128 * 64];   // 16 KB

  const int lane = tid & 63;
  const int wid = tid >> 6;
  const int wr = wid >> 1, wc = wid & 1;

  int ldsoff[4]; size_t abase[4]; size_t bbase[4];
#pragma unroll
  for (int j = 0; j < 4; ++j) {
    int boff = j * 4096 + wid * 1024 + lane * 16;
    int row = boff >> 7;                          // 0..127
    int c = ((boff >> 4) & 7) ^ (row & 7);
    ldsoff[j] = (j * 4096 + wid * 1024) >> 1;
    int ar = rowbase + row; if (ar > Ne - 1) ar = Ne - 1;
    int tok = list[seg0 + ar] >> 1;
    abase[j] = (size_t)tok * DDIM + c * 8;
    bbase[j] = (size_t)(e * FDIM + f0 + row) * DDIM + c * 8;
  }

  f32x4 acc1[4][4], acc3[4][4];
  const f32x4 z = {0.f, 0.f, 0.f, 0.f};
#pragma unroll
  for (int m = 0; m < 4; ++m)
#pragma unroll
    for (int n = 0; n < 4; ++n) { acc1[m][n] = z; acc3[m][n] = z; }

  const int lrow = lane & 15;
  const int kb = (lane >> 4) * 8;
  for (int kt = 0; kt < DDIM / 64; ++kt) {
    const int ko = kt * 64;
#pragma unroll
    for (int j = 0; j < 4; ++j) {
      gload_lds16(Xb + abase[j] + ko, &As[ldsoff[j]]);
      gload_lds16(W1b + bbase[j] + ko, &B1s[ldsoff[j]]);
      gload_lds16(W3b + bbase[j] + ko, &B3s[ldsoff[j]]);
    }
    __syncthreads();
#pragma unroll
    for (int ks = 0; ks < 2; ++ks) {
      bf16x8 a[4];
#pragma unroll
      for (int m = 0; m < 4; ++m)
        a[m] = frag_ld(As, wr * 64 + m * 16 + lrow, ks * 32 + kb);
#pragma unroll
      for (int n = 0; n < 4; ++n) {
        bf16x8 p = frag_ld(B1s, wc * 64 + n * 16 + lrow, ks * 32 + kb);
        bf16x8 q = frag_ld(B3s, wc * 64 + n * 16 + lrow, ks * 32 + kb);
#pragma unroll
        for (int m = 0; m < 4; ++m) {
          acc1[m][n] = __builtin_amdgcn_mfma_f32_16x16x32_bf16(a[m], p, acc1[m][n], 0, 0, 0);
          acc3[m][n] = __builtin_amdgcn_mfma_f32_16x16x32_bf16(a[m], q, acc3[m][n], 0, 0, 0);
        }
      }
    }
    __syncthreads();
  }

  // epilogue: SiLU(h1)*h3 -> bf16 H (C/D layout: col=lane&15, row=(lane>>4)*4+r)
#pragma unroll
  for (int m = 0; m < 4; ++m)
#pragma unroll
    for (int r = 0; r < 4; ++r) {
      int rloc = wr * 64 + m * 16 + ((lane >> 4) << 2) + r;
      if (rowbase + rloc < Ne) {
#pragma unroll
        for (int n = 0; n < 4; ++n) {
          float v1 = acc1[m][n][r], v3 = acc3[m][n][r];
          float h = v1 / (1.f + __expf(-v1)) * v3;
          int col = f0 + wc * 64 + n * 16 + (lane & 15);
          Hb[(size_t)(seg0 + rowbase + rloc) * FDIM + col] = f2bf(h);
        }
      }
    }
}

// ---------------- GEMM2: Y[(t<<1)|k] = gate * (H w2^T), bf16 out, NO atomics ----------------
// BM=128, BN=64, BK=64. Depth-2 counted-vmcnt pipeline, 6 gloads/wave/tile, 48 KB LDS.
__global__ __launch_bounds__(256) void gemm2_kernel(
    const unsigned short* __restrict__ Hb, const unsigned short* __restrict__ W2b,
    unsigned short* __restrict__ Yb, const int* __restrict__ off,
    const int* __restrict__ list, const float* __restrict__ rgate,
    const int* __restrict__ wmap, const int* __restrict__ nwp) {
  const int bid0 = blockIdx.x;
  const int slot = bid0 >> 4;     // 72 rowtile slots
  const int dt = bid0 & 15;       // 16 d-col tiles
  if (slot >= nwp[0]) return;
  const int ent = wmap[slot];
  const int e = ent >> 8;
  const int rt = ent & 255;
  const int seg0 = off[e];
  const int Ne = off[e + 1] - seg0;
  const int rowbase = rt * 128;
  const int d0 = dt * 64;

  __shared__ unsigned short As[2][128 * 64];   // 32 KB
  __shared__ unsigned short Bs[2][64 * 64];    // 16 KB

  const int tid = threadIdx.x;
  const int lane = tid & 63;
  const int wid = tid >> 6;
  const int wr = wid >> 1, wc = wid & 1;

  int ldsoffA[4]; size_t abase[4];
  int ldsoffB[2]; size_t bbase[2];
#pragma unroll
  for (int j = 0; j < 4; ++j) {
    int boff = j * 4096 + wid * 1024 + lane * 16;
    int row = boff >> 7;
    int c = ((boff >> 4) & 7) ^ (row & 7);
    ldsoffA[j] = (j * 4096 + wid * 1024) >> 1;
    int ar = rowbase + row; if (ar > Ne - 1) ar = Ne - 1;
    abase[j] = (size_t)(seg0 + ar) * FDIM + c * 8;
  }
#pragma unroll
  for (int j = 0; j < 2; ++j) {
    int boff = j * 4096 + wid * 1024 + lane * 16;
    int row = boff >> 7;
    int c = ((boff >> 4) & 7) ^ (row & 7);
    ldsoffB[j] = (j * 4096 + wid * 1024) >> 1;
    bbase[j] = (size_t)(e * DDIM + d0 + row) * FDIM + c * 8;
  }

  f32x4 acc[4][2];
  const f32x4 z = {0.f, 0.f, 0.f, 0.f};
#pragma unroll
  for (int m = 0; m < 4; ++m)
#pragma unroll
    for (int n = 0; n < 2; ++n) acc[m][n] = z;

  auto stage = [&](int buf, int kt) {
    const int ko = kt * 64;
#pragma unroll
    for (int j = 0; j < 4; ++j)
      gload_lds16(Hb + abase[j] + ko, &As[buf][ldsoffA[j]]);
#pragma unroll
    for (int j = 0; j < 2; ++j)
      gload_lds16(W2b + bbase[j] + ko, &Bs[buf][ldsoffB[j]]);
  };

  const int lrow = lane & 15;
  const int kb = (lane >> 4) * 8;

  vwait0();
  stage(0, 0);              // 6 in flight
  stage(1, 1);              // 12 in flight
  vwait6();
  barr();

  for (int t = 0; t < 16; ++t) {
    const int b = t & 1;
#pragma unroll
    for (int ks = 0; ks < 2; ++ks) {
      bf16x8 a[4], bb[2];
#pragma unroll
      for (int m = 0; m < 4; ++m)
        a[m] = frag_ld(As[b], wr * 64 + m * 16 + lrow, ks * 32 + kb);
#pragma unroll
      for (int n = 0; n < 2; ++n)
        bb[n] = frag_ld(Bs[b], wc * 32 + n * 16 + lrow, ks * 32 + kb);
#pragma unroll
      for (int m = 0; m < 4; ++m)
#pragma unroll
        for (int n = 0; n < 2; ++n)
          acc[m][n] = __builtin_amdgcn_mfma_f32_16x16x32_bf16(a[m], bb[n], acc[m][n], 0, 0, 0);
    }
    if (t == 15) break;
    lwait0();
    barr();
    if (t + 2 < 16) stage(b, t + 2);
    if (t < 14) vwait6(); else vwait0();
    barr();
  }

  // epilogue: scale by gate, store bf16 into Y[(t<<1)|k] (rg <-> (t,k) bijective)
#pragma unroll
  for (int m = 0; m < 4; ++m)
#pragma unroll
    for (int r = 0; r < 4; ++r) {
      int rloc = wr * 64 + m * 16 + ((lane >> 4) << 2) + r;
      if (rowbase + rloc < Ne) {
        int rg = seg0 + rowbase + rloc;
        int tk = list[rg];
        float gsc = rgate[rg];
#pragma unroll
        for (int n = 0; n < 2; ++n) {
          int col = d0 + wc * 32 + n * 16 + (lane & 15);
          Yb[(size_t)tk * DDIM + col] = f2bf(gsc * acc[m][n][r]);
        }
      }
    }
}

// ---------------- combine: out[t] = Y[2t] + Y[2t+1]  (bf16 in, fp32 out) ----------------
__global__ __launch_bounds__(256) void combine_kernel(const unsigned short* __restrict__ Yb,
                                                      float* __restrict__ out) {
  const int n = T_TOK * DDIM / 8;   // groups of 8 elements
  const int stride = gridDim.x * blockDim.x;
  for (int i = blockIdx.x * blockDim.x + threadIdx.x; i < n; i += stride) {
    int t = i >> 7;                 // 128 groups per token row
    int c = (i & 127) * 8;
    u16x8 a = *reinterpret_cast<const u16x8*>(Yb + ((size_t)t * 2) * DDIM + c);
    u16x8 b = *reinterpret_cast<const u16x8*>(Yb + ((size_t)t * 2 + 1) * DDIM + c);
    float4 o0, o1;
    o0.x = bf2f(a[0]) + bf2f(b[0]); o0.y = bf2f(a[1]) + bf2f(b[1]);
    o0.z = bf2f(a[2]) + bf2f(b[2]); o0.w = bf2f(a[3]) + bf2f(b[3]);
    o1.x = bf2f(a[4]) + bf2f(b[4]); o1.y = bf2f(a[5]) + bf2f(b[5]);
    o1.z = bf2f(a[6]) + bf2f(b[6]); o1.w = bf2f(a[7]) + bf2f(b[7]);
    float* dst = out + (size_t)t * DDIM + c;
    *reinterpret_cast<float4*>(dst) = o0;
    *reinterpret_cast<float4*>(dst + 4) = o1;
  }
}

extern "C" void kernel_launch(void* const* d_in, const int* in_sizes, int n_in,
                              void* d_out, int out_size, void* d_ws, size_t ws_size,
                              hipStream_t stream) {
  (void)in_sizes; (void)n_in; (void)ws_size; (void)out_size;
  const float* x  = (const float*)d_in[0];
  const float* gw = (const float*)d_in[1];
  const float* w1 = (const float*)d_in[2];
  const float* w3 = (const float*)d_in[3];
  const float* w2 = (const float*)d_in[4];
  float* out = (float*)d_out;

  char* ws = (char*)d_ws;
  unsigned short* Xb  = (unsigned short*)(ws + 0);            //  8 MB
  unsigned short* W1b = (unsigned short*)(ws + 8388608);      // 16 MB
  unsigned short* W3b = (unsigned short*)(ws + 25165824);     // 16 MB
  unsigned short* W2b = (unsigned short*)(ws + 41943040);     // 16 MB
  unsigned short* Hb  = (unsigned short*)(ws + 58720256);     // 16 MB
  // Yb (16.8 MB bf16) overlays W1b — dead once gemm1 finishes.
  unsigned short* Yb  = (unsigned short*)(ws + 8388608);
  int*   ctrl  = (int*)(ws + 75497472);
  int*   off   = ctrl;           // off[0..8] (written by fill block 0)
  int*   nwp   = ctrl + 12;      // work-list count
  int*   curp  = ctrl + 16;      // curp[e*32], 128B-padded (zeroed in prep)
  int*   wmap  = ctrl + 256;     // <=72 packed (e<<8|rowtile) entries
  int*   tkidx = (int*)(ws + 75497472 + 4096);
  float* tkw   = (float*)(ws + 75497472 + 4096 + 32768);
  int*   list  = (int*)(ws + 75497472 + 4096 + 65536);
  float* rgate = (float*)(ws + 75497472 + 4096 + 98304);

  prep_kernel<<<3072, 256, 0, stream>>>(w1, w3, W1b, W3b,
                                        x, gw, (unsigned int*)Xb, tkidx, tkw, curp);
  fill_kernel<<<16, 256, 0, stream>>>(tkidx, tkw, off, curp, list, rgate, wmap, nwp);

  gemm1_kernel<<<72 * 8 + 1024, 256, 0, stream>>>(Xb, W1b, W3b, Hb, off, list,
                                                  wmap, nwp, w2, W2b);
  gemm2_kernel<<<72 * 16, 256, 0, stream>>>(Hb, W2b, Yb, off, list, rgate, wmap, nwp);
  combine_kernel<<<2048, 256, 0, stream>>>(Yb, out);
}

// Round 5
// 160.962 us; speedup vs baseline: 1.0329x; 1.0329x over previous
//
#include <hip/hip_runtime.h>
#include <hip/hip_bf16.h>
#include <cstdint>
#include <cstddef>

// Problem constants (B,S,D,F,E,K) = (2,2048,1024,1024,8,2)
#define T_TOK 4096
#define DDIM  1024
#define FDIM  1024
#define NEXP  8

typedef __attribute__((ext_vector_type(8))) short bf16x8;
typedef __attribute__((ext_vector_type(4))) float f32x4;
typedef __attribute__((ext_vector_type(8))) unsigned short u16x8;

__device__ __forceinline__ unsigned short f2bf(float f) {
  unsigned int u = __float_as_uint(f);
  u += 0x7FFFu + ((u >> 16) & 1u);   // RNE
  return (unsigned short)(u >> 16);
}
__device__ __forceinline__ float bf2f(unsigned short u) {
  return __uint_as_float(((unsigned int)u) << 16);
}

__device__ __forceinline__ void gload_lds16(const void* g, void* l) {
  __builtin_amdgcn_global_load_lds(
      (const __attribute__((address_space(1))) unsigned int*)g,
      (__attribute__((address_space(3))) unsigned int*)l, 16, 0, 0);
}

// raw sync primitives (counted-vmcnt pipelines)
__device__ __forceinline__ void vwait6() { asm volatile("s_waitcnt vmcnt(6)" ::: "memory"); }
__device__ __forceinline__ void vwait4() { asm volatile("s_waitcnt vmcnt(4)" ::: "memory"); }
__device__ __forceinline__ void vwait0() { asm volatile("s_waitcnt vmcnt(0)" ::: "memory"); }
__device__ __forceinline__ void lwait0() { asm volatile("s_waitcnt lgkmcnt(0)" ::: "memory"); }
__device__ __forceinline__ void barr()   { asm volatile("s_barrier" ::: "memory"); }

// swizzled fragment read: tile rows are 64 bf16 = 128B; byte ^= ((row&7)<<4)
// matches the pre-swizzled global source in the staging loops (rule #21).
__device__ __forceinline__ bf16x8 frag_ld(const unsigned short* tile, int row, int kk) {
  int byteoff = (row << 7) + ((kk * 2) ^ ((row & 7) << 4));
  return *reinterpret_cast<const bf16x8*>(reinterpret_cast<const char*>(tile) + byteoff);
}

// ---------------- prep: w1/w3 fp32->bf16 (blocks 0..2047) + gate (blocks 2048..3071) ----
// w2 conversion lives in gemm1's dispatch (rides in gemm1's HBM-BW shadow).
__global__ __launch_bounds__(256) void prep_kernel(
    const float* __restrict__ w1, const float* __restrict__ w3,
    unsigned short* __restrict__ W1b, unsigned short* __restrict__ W3b,
    const float* __restrict__ x, const float* __restrict__ gw,
    unsigned int* __restrict__ Xb32, int* __restrict__ tkidx, float* __restrict__ tkw,
    int* __restrict__ curp) {
  __shared__ float gws[NEXP * DDIM];   // 32 KB (gate blocks only)
  const int bid = blockIdx.x;
  const int tid = threadIdx.x;

  if (bid < 2048) {
    // ---- weight conversion: 1024 blocks per matrix (w1, w3) ----
    const int sub = bid >> 10;
    const int b = bid & 1023;
    const float* s = (sub == 0) ? w1 : w3;
    unsigned short* d = (sub == 0) ? W1b : W3b;
    const int n = NEXP * FDIM * DDIM;
    const int stride = 1024 * 256 * 8;
    for (int i = (b * 256 + tid) * 8; i < n; i += stride) {
      float4 a = *reinterpret_cast<const float4*>(s + i);
      float4 c = *reinterpret_cast<const float4*>(s + i + 4);
      u16x8 o;
      o[0] = f2bf(a.x); o[1] = f2bf(a.y); o[2] = f2bf(a.z); o[3] = f2bf(a.w);
      o[4] = f2bf(c.x); o[5] = f2bf(c.y); o[6] = f2bf(c.z); o[7] = f2bf(c.w);
      *reinterpret_cast<u16x8*>(d + i) = o;
    }
    return;
  }

  // ---- gate: 1024 blocks, 1 token per wave ----
  const int lane = tid & 63;
  const int wid = tid >> 6;
  if (bid == 2048 && tid < NEXP) curp[tid * 32] = 0;   // zero padded cursors for fill
  for (int i = tid; i < NEXP * DDIM / 4; i += 256)
    reinterpret_cast<float4*>(gws)[i] = reinterpret_cast<const float4*>(gw)[i];
  __syncthreads();

  const int t = (bid - 2048) * 4 + wid;
  const float2* xr = reinterpret_cast<const float2*>(x + (size_t)t * DDIM);
  float2 xv[8];
#pragma unroll
  for (int i = 0; i < 8; ++i) xv[i] = xr[i * 64 + lane];
  // fused x -> bf16 (packed pair store, coalesced 4B/lane)
#pragma unroll
  for (int i = 0; i < 8; ++i)
    Xb32[(size_t)t * 512 + i * 64 + lane] =
        (unsigned int)f2bf(xv[i].x) | ((unsigned int)f2bf(xv[i].y) << 16);
  float p[NEXP];
#pragma unroll
  for (int e = 0; e < NEXP; ++e) p[e] = 0.f;
#pragma unroll
  for (int i = 0; i < 8; ++i) {
    const int k = (i * 64 + lane) * 2;
#pragma unroll
    for (int e = 0; e < NEXP; ++e)
      p[e] += xv[i].x * gws[e * DDIM + k] + xv[i].y * gws[e * DDIM + k + 1];
  }
#pragma unroll
  for (int s = 32; s > 0; s >>= 1)
#pragma unroll
    for (int e = 0; e < NEXP; ++e) p[e] += __shfl_xor(p[e], s, 64);
  if (lane == 0) {
    int i0 = 0; float l0 = p[0];
#pragma unroll
    for (int e = 1; e < NEXP; ++e) if (p[e] > l0) { l0 = p[e]; i0 = e; }
    int i1 = -1; float l1 = -1e30f;
#pragma unroll
    for (int e = 0; e < NEXP; ++e) if (e != i0 && p[e] > l1) { l1 = p[e]; i1 = e; }
    float ex = __expf(l1 - l0);            // <= 1
    float w0 = 1.f / (1.f + ex);
    float w1v = ex / (1.f + ex);
    tkidx[t * 2] = i0; tkidx[t * 2 + 1] = i1;
    tkw[t * 2] = w0;   tkw[t * 2 + 1] = w1v;
  }
}

// ---------------- fill: global hist + off + compaction + compact work list ----------------
__global__ __launch_bounds__(256) void fill_kernel(const int* __restrict__ tkidx,
                                                   const float* __restrict__ tkw,
                                                   int* __restrict__ offp,
                                                   int* __restrict__ curp,
                                                   int* __restrict__ list,
                                                   float* __restrict__ rgate,
                                                   int* __restrict__ wmap,
                                                   int* __restrict__ nwp) {
  __shared__ int ghist[4][NEXP];
  __shared__ int lhist[NEXP], base[NEXP];
  const int tid = threadIdx.x;
  if (tid < 32) ghist[tid >> 3][tid & 7] = 0;
  if (tid < NEXP) lhist[tid] = 0;
  __syncthreads();
  for (int i = tid; i < 2 * T_TOK; i += 256)
    atomicAdd(&ghist[tid >> 6][tkidx[i]], 1);
  const int t = blockIdx.x * 256 + tid;
  const int e0 = tkidx[t * 2], e1 = tkidx[t * 2 + 1];
  const int r0 = atomicAdd(&lhist[e0], 1);
  const int r1 = atomicAdd(&lhist[e1], 1);
  __syncthreads();
  if (blockIdx.x == 0 && tid == 64) {
    // build compact (expert, rowtile) work list
    int nw = 0;
    for (int e = 0; e < NEXP; ++e) {
      int c = ghist[0][e] + ghist[1][e] + ghist[2][e] + ghist[3][e];
      int nrt = (c + 127) >> 7;
      for (int r = 0; r < nrt; ++r) wmap[nw++] = (e << 8) | r;
    }
    nwp[0] = nw;
  }
  if (tid < NEXP) {
    int o = 0;
#pragma unroll
    for (int j = 0; j < NEXP; ++j) {
      int c = ghist[0][j] + ghist[1][j] + ghist[2][j] + ghist[3][j];
      if (j < tid) o += c;
    }
    if (blockIdx.x == 0) {
      offp[tid] = o;
      if (tid == NEXP - 1)
        offp[NEXP] = o + ghist[0][tid] + ghist[1][tid] + ghist[2][tid] + ghist[3][tid];
    }
    base[tid] = o + atomicAdd(&curp[tid * 32], lhist[tid]);
  }
  __syncthreads();
  const int p0 = base[e0] + r0;
  const int p1 = base[e1] + r1;
  list[p0] = (t << 1);     rgate[p0] = tkw[t * 2];
  list[p1] = (t << 1) | 1; rgate[p1] = tkw[t * 2 + 1];
}

// ---------------- GEMM1: H = silu(X w1^T) * (X w3^T), gathered rows ----------------
// BM=128 tokens, BN=64 f-cols, BK=64 (round-2's proven tile/waves/epilogue).
// Pipeline: A double-buffered via gload_lds (2x16 KB), B1/B3 reg-staged (T14
// issue-early / ds_write-late) into single 8 KB buffers. 48 KB LDS -> 3 blocks/CU.
// Per tile: issue A(t+1)+B(t+1) BEFORE the barrier (pinned by asm barrier),
// MFMA on tile t, then counted vmcnt(4) (drains A(t+1), leaves B(t+1) regs in
// flight; compiler inserts the counted wait before next ds_write). No vmcnt(0)
// in the main loop -> the round-2 per-tile drain stall is covered by compute.
// Blocks >= 72*16 convert w2 fp32->bf16 (rides in gemm1's HBM shadow).
__global__ __launch_bounds__(256) void gemm1_kernel(
    const unsigned short* __restrict__ Xb, const unsigned short* __restrict__ W1b,
    const unsigned short* __restrict__ W3b, unsigned short* __restrict__ Hb,
    const int* __restrict__ off, const int* __restrict__ list,
    const int* __restrict__ wmap, const int* __restrict__ nwp,
    const float* __restrict__ w2, unsigned short* __restrict__ W2b) {
  const int bid0 = blockIdx.x;
  const int tid = threadIdx.x;

  if (bid0 >= 72 * 16) {
    // ---- embedded w2 fp32->bf16 conversion (1024 blocks) ----
    const int b = bid0 - 72 * 16;
    const int n = NEXP * FDIM * DDIM;
    const int stride = 1024 * 256 * 8;
    for (int i = (b * 256 + tid) * 8; i < n; i += stride) {
      float4 a = *reinterpret_cast<const float4*>(w2 + i);
      float4 c = *reinterpret_cast<const float4*>(w2 + i + 4);
      u16x8 o;
      o[0] = f2bf(a.x); o[1] = f2bf(a.y); o[2] = f2bf(a.z); o[3] = f2bf(a.w);
      o[4] = f2bf(c.x); o[5] = f2bf(c.y); o[6] = f2bf(c.z); o[7] = f2bf(c.w);
      *reinterpret_cast<u16x8*>(W2b + i) = o;
    }
    return;
  }

  const int slot = bid0 >> 4;     // 72 rowtile slots
  const int ft = bid0 & 15;       // 16 f-col tiles of 64
  if (slot >= nwp[0]) return;
  const int ent = wmap[slot];
  const int e = ent >> 8;
  const int rt = ent & 255;
  const int seg0 = off[e];
  const int Ne = off[e + 1] - seg0;
  const int rowbase = rt * 128;   // < Ne by wmap construction
  const int f0 = ft * 64;

  __shared__ unsigned short As[2][128 * 64];   // 32 KB (double-buffered)
  __shared__ unsigned short B1s[64 * 64];      //  8 KB
  __shared__ unsigned short B3s[64 * 64];      //  8 KB

  const int lane = tid & 63;
  const int wid = tid >> 6;
  const int wr = wid >> 1, wc = wid & 1;

  int ldsoffA[4]; size_t abase[4];
#pragma unroll
  for (int j = 0; j < 4; ++j) {
    int boff = j * 4096 + wid * 1024 + lane * 16;
    int row = boff >> 7;
    int c = ((boff >> 4) & 7) ^ (row & 7);
    ldsoffA[j] = (j * 4096 + wid * 1024) >> 1;
    int ar = rowbase + row; if (ar > Ne - 1) ar = Ne - 1;
    int tok = list[seg0 + ar] >> 1;
    abase[j] = (size_t)tok * DDIM + c * 8;
  }
  size_t bsrc[2]; int ldsWB[2];
#pragma unroll
  for (int j = 0; j < 2; ++j) {
    int boff = j * 4096 + wid * 1024 + lane * 16;
    int row = boff >> 7;
    int c = ((boff >> 4) & 7) ^ (row & 7);
    ldsWB[j] = boff >> 1;   // per-thread swizzle-image dest (ds_write)
    bsrc[j] = (size_t)(e * FDIM + f0 + row) * DDIM + c * 8;
  }

  f32x4 acc1[4][2], acc3[4][2];
  const f32x4 z = {0.f, 0.f, 0.f, 0.f};
#pragma unroll
  for (int m = 0; m < 4; ++m)
#pragma unroll
    for (int n = 0; n < 2; ++n) { acc1[m][n] = z; acc3[m][n] = z; }

  const int lrow = lane & 15;
  const int kb = (lane >> 4) * 8;

  // ---- prologue: issue A(0) (gload_lds) then B(0) (regs); drain A only ----
  vwait0();
#pragma unroll
  for (int j = 0; j < 4; ++j)
    gload_lds16(Xb + abase[j], &As[0][ldsoffA[j]]);
  bf16x8 bc1[2], bc3[2], bn1[2], bn3[2];
#pragma unroll
  for (int j = 0; j < 2; ++j) {
    bc1[j] = *reinterpret_cast<const bf16x8*>(W1b + bsrc[j]);
    bc3[j] = *reinterpret_cast<const bf16x8*>(W3b + bsrc[j]);
  }
  vwait4();   // A(0)'s 4 gload_lds done; B(0)'s 4 reg loads stay in flight

#pragma unroll 2
  for (int kt = 0; kt < 16; ++kt) {
    const int cur = kt & 1;
    // (a) issue next A tile into the other buffer (readers finished last iter)
    if (kt < 15) {
      const int ko = (kt + 1) * 64;
#pragma unroll
      for (int j = 0; j < 4; ++j)
        gload_lds16(Xb + abase[j] + ko, &As[cur ^ 1][ldsoffA[j]]);
      // (b) issue next B tiles into regs
#pragma unroll
      for (int j = 0; j < 2; ++j) {
        bn1[j] = *reinterpret_cast<const bf16x8*>(W1b + bsrc[j] + ko);
        bn3[j] = *reinterpret_cast<const bf16x8*>(W3b + bsrc[j] + ko);
      }
    }
    // (c) write current B regs -> LDS (compiler inserts counted vmcnt for bc)
#pragma unroll
    for (int j = 0; j < 2; ++j) {
      *reinterpret_cast<bf16x8*>(&B1s[ldsWB[j]]) = bc1[j];
      *reinterpret_cast<bf16x8*>(&B3s[ldsWB[j]]) = bc3[j];
    }
    lwait0();
    barr();
    // (e) MFMA on tile kt
#pragma unroll
    for (int ks = 0; ks < 2; ++ks) {
      bf16x8 a[4], p[2], q[2];
#pragma unroll
      for (int m = 0; m < 4; ++m)
        a[m] = frag_ld(As[cur], wr * 64 + m * 16 + lrow, ks * 32 + kb);
#pragma unroll
      for (int n = 0; n < 2; ++n) {
        p[n] = frag_ld(B1s, wc * 32 + n * 16 + lrow, ks * 32 + kb);
        q[n] = frag_ld(B3s, wc * 32 + n * 16 + lrow, ks * 32 + kb);
      }
#pragma unroll
      for (int m = 0; m < 4; ++m)
#pragma unroll
        for (int n = 0; n < 2; ++n) {
          acc1[m][n] = __builtin_amdgcn_mfma_f32_16x16x32_bf16(a[m], p[n], acc1[m][n], 0, 0, 0);
          acc3[m][n] = __builtin_amdgcn_mfma_f32_16x16x32_bf16(a[m], q[n], acc3[m][n], 0, 0, 0);
        }
    }
    if (kt == 15) break;
    // (f) counted wait: drain A(kt+1) (oldest 4), leave B(kt+1) regs in flight
    vwait4();
    barr();
#pragma unroll
    for (int j = 0; j < 2; ++j) { bc1[j] = bn1[j]; bc3[j] = bn3[j]; }
  }

  // epilogue: SiLU(h1)*h3 -> bf16 H (C/D layout: col=lane&15, row=(lane>>4)*4+r)
#pragma unroll
  for (int m = 0; m < 4; ++m)
#pragma unroll
    for (int n = 0; n < 2; ++n)
#pragma unroll
      for (int r = 0; r < 4; ++r) {
        int rloc = wr * 64 + m * 16 + ((lane >> 4) << 2) + r;
        if (rowbase + rloc < Ne) {
          float v1 = acc1[m][n][r], v3 = acc3[m][n][r];
          float h = v1 / (1.f + __expf(-v1)) * v3;
          int col = f0 + wc * 32 + n * 16 + (lane & 15);
          Hb[(size_t)(seg0 + rowbase + rloc) * FDIM + col] = f2bf(h);
        }
      }
}

// ---------------- GEMM2: Y[(t<<1)|k] = gate * (H w2^T), bf16 out, NO atomics ----------------
// BM=128, BN=64, BK=64. Depth-2 counted-vmcnt pipeline, 6 gloads/wave/tile, 48 KB LDS.
__global__ __launch_bounds__(256) void gemm2_kernel(
    const unsigned short* __restrict__ Hb, const unsigned short* __restrict__ W2b,
    unsigned short* __restrict__ Yb, const int* __restrict__ off,
    const int* __restrict__ list, const float* __restrict__ rgate,
    const int* __restrict__ wmap, const int* __restrict__ nwp) {
  const int bid0 = blockIdx.x;
  const int slot = bid0 >> 4;     // 72 rowtile slots
  const int dt = bid0 & 15;       // 16 d-col tiles
  if (slot >= nwp[0]) return;
  const int ent = wmap[slot];
  const int e = ent >> 8;
  const int rt = ent & 255;
  const int seg0 = off[e];
  const int Ne = off[e + 1] - seg0;
  const int rowbase = rt * 128;
  const int d0 = dt * 64;

  __shared__ unsigned short As[2][128 * 64];   // 32 KB
  __shared__ unsigned short Bs[2][64 * 64];    // 16 KB

  const int tid = threadIdx.x;
  const int lane = tid & 63;
  const int wid = tid >> 6;
  const int wr = wid >> 1, wc = wid & 1;

  int ldsoffA[4]; size_t abase[4];
  int ldsoffB[2]; size_t bbase[2];
#pragma unroll
  for (int j = 0; j < 4; ++j) {
    int boff = j * 4096 + wid * 1024 + lane * 16;
    int row = boff >> 7;
    int c = ((boff >> 4) & 7) ^ (row & 7);
    ldsoffA[j] = (j * 4096 + wid * 1024) >> 1;
    int ar = rowbase + row; if (ar > Ne - 1) ar = Ne - 1;
    abase[j] = (size_t)(seg0 + ar) * FDIM + c * 8;
  }
#pragma unroll
  for (int j = 0; j < 2; ++j) {
    int boff = j * 4096 + wid * 1024 + lane * 16;
    int row = boff >> 7;
    int c = ((boff >> 4) & 7) ^ (row & 7);
    ldsoffB[j] = (j * 4096 + wid * 1024) >> 1;
    bbase[j] = (size_t)(e * DDIM + d0 + row) * FDIM + c * 8;
  }

  f32x4 acc[4][2];
  const f32x4 z = {0.f, 0.f, 0.f, 0.f};
#pragma unroll
  for (int m = 0; m < 4; ++m)
#pragma unroll
    for (int n = 0; n < 2; ++n) acc[m][n] = z;

  auto stage = [&](int buf, int kt) {
    const int ko = kt * 64;
#pragma unroll
    for (int j = 0; j < 4; ++j)
      gload_lds16(Hb + abase[j] + ko, &As[buf][ldsoffA[j]]);
#pragma unroll
    for (int j = 0; j < 2; ++j)
      gload_lds16(W2b + bbase[j] + ko, &Bs[buf][ldsoffB[j]]);
  };

  const int lrow = lane & 15;
  const int kb = (lane >> 4) * 8;

  vwait0();
  stage(0, 0);              // 6 in flight
  stage(1, 1);              // 12 in flight
  vwait6();
  barr();

  for (int t = 0; t < 16; ++t) {
    const int b = t & 1;
#pragma unroll
    for (int ks = 0; ks < 2; ++ks) {
      bf16x8 a[4], bb[2];
#pragma unroll
      for (int m = 0; m < 4; ++m)
        a[m] = frag_ld(As[b], wr * 64 + m * 16 + lrow, ks * 32 + kb);
#pragma unroll
      for (int n = 0; n < 2; ++n)
        bb[n] = frag_ld(Bs[b], wc * 32 + n * 16 + lrow, ks * 32 + kb);
#pragma unroll
      for (int m = 0; m < 4; ++m)
#pragma unroll
        for (int n = 0; n < 2; ++n)
          acc[m][n] = __builtin_amdgcn_mfma_f32_16x16x32_bf16(a[m], bb[n], acc[m][n], 0, 0, 0);
    }
    if (t == 15) break;
    lwait0();
    barr();
    if (t + 2 < 16) stage(b, t + 2);
    if (t < 14) vwait6(); else vwait0();
    barr();
  }

  // epilogue: scale by gate, store bf16 into Y[(t<<1)|k] (rg <-> (t,k) bijective)
#pragma unroll
  for (int m = 0; m < 4; ++m)
#pragma unroll
    for (int r = 0; r < 4; ++r) {
      int rloc = wr * 64 + m * 16 + ((lane >> 4) << 2) + r;
      if (rowbase + rloc < Ne) {
        int rg = seg0 + rowbase + rloc;
        int tk = list[rg];
        float gsc = rgate[rg];
#pragma unroll
        for (int n = 0; n < 2; ++n) {
          int col = d0 + wc * 32 + n * 16 + (lane & 15);
          Yb[(size_t)tk * DDIM + col] = f2bf(gsc * acc[m][n][r]);
        }
      }
    }
}

// ---------------- combine: out[t] = Y[2t] + Y[2t+1]  (bf16 in, fp32 out) ----------------
__global__ __launch_bounds__(256) void combine_kernel(const unsigned short* __restrict__ Yb,
                                                      float* __restrict__ out) {
  const int n = T_TOK * DDIM / 8;   // groups of 8 elements
  const int stride = gridDim.x * blockDim.x;
  for (int i = blockIdx.x * blockDim.x + threadIdx.x; i < n; i += stride) {
    int t = i >> 7;                 // 128 groups per token row
    int c = (i & 127) * 8;
    u16x8 a = *reinterpret_cast<const u16x8*>(Yb + ((size_t)t * 2) * DDIM + c);
    u16x8 b = *reinterpret_cast<const u16x8*>(Yb + ((size_t)t * 2 + 1) * DDIM + c);
    float4 o0, o1;
    o0.x = bf2f(a[0]) + bf2f(b[0]); o0.y = bf2f(a[1]) + bf2f(b[1]);
    o0.z = bf2f(a[2]) + bf2f(b[2]); o0.w = bf2f(a[3]) + bf2f(b[3]);
    o1.x = bf2f(a[4]) + bf2f(b[4]); o1.y = bf2f(a[5]) + bf2f(b[5]);
    o1.z = bf2f(a[6]) + bf2f(b[6]); o1.w = bf2f(a[7]) + bf2f(b[7]);
    float* dst = out + (size_t)t * DDIM + c;
    *reinterpret_cast<float4*>(dst) = o0;
    *reinterpret_cast<float4*>(dst + 4) = o1;
  }
}

extern "C" void kernel_launch(void* const* d_in, const int* in_sizes, int n_in,
                              void* d_out, int out_size, void* d_ws, size_t ws_size,
                              hipStream_t stream) {
  (void)in_sizes; (void)n_in; (void)ws_size; (void)out_size;
  const float* x  = (const float*)d_in[0];
  const float* gw = (const float*)d_in[1];
  const float* w1 = (const float*)d_in[2];
  const float* w3 = (const float*)d_in[3];
  const float* w2 = (const float*)d_in[4];
  float* out = (float*)d_out;

  char* ws = (char*)d_ws;
  unsigned short* Xb  = (unsigned short*)(ws + 0);            //  8 MB
  unsigned short* W1b = (unsigned short*)(ws + 8388608);      // 16 MB
  unsigned short* W3b = (unsigned short*)(ws + 25165824);     // 16 MB
  unsigned short* W2b = (unsigned short*)(ws + 41943040);     // 16 MB
  unsigned short* Hb  = (unsigned short*)(ws + 58720256);     // 16 MB
  // Yb (16.8 MB bf16) overlays W1b — dead once gemm1 finishes.
  unsigned short* Yb  = (unsigned short*)(ws + 8388608);
  int*   ctrl  = (int*)(ws + 75497472);
  int*   off   = ctrl;           // off[0..8] (written by fill block 0)
  int*   nwp   = ctrl + 12;      // work-list count
  int*   curp  = ctrl + 16;      // curp[e*32], 128B-padded (zeroed in prep)
  int*   wmap  = ctrl + 256;     // <=72 packed (e<<8|rowtile) entries
  int*   tkidx = (int*)(ws + 75497472 + 4096);
  float* tkw   = (float*)(ws + 75497472 + 4096 + 32768);
  int*   list  = (int*)(ws + 75497472 + 4096 + 65536);
  float* rgate = (float*)(ws + 75497472 + 4096 + 98304);

  prep_kernel<<<3072, 256, 0, stream>>>(w1, w3, W1b, W3b,
                                        x, gw, (unsigned int*)Xb, tkidx, tkw, curp);
  fill_kernel<<<16, 256, 0, stream>>>(tkidx, tkw, off, curp, list, rgate, wmap, nwp);

  gemm1_kernel<<<72 * 16 + 1024, 256, 0, stream>>>(Xb, W1b, W3b, Hb, off, list,
                                                   wmap, nwp, w2, W2b);
  gemm2_kernel<<<72 * 16, 256, 0, stream>>>(Hb, W2b, Yb, off, list, rgate, wmap, nwp);
  combine_kernel<<<2048, 256, 0, stream>>>(Yb, out);
}

// Round 6
// 133.321 us; speedup vs baseline: 1.2470x; 1.2073x over previous
//
#include <hip/hip_runtime.h>
#include <hip/hip_bf16.h>
#include <cstdint>
#include <cstddef>

// Problem constants (B,S,D,F,E,K) = (2,2048,1024,1024,8,2)
#define T_TOK 4096
#define DDIM  1024
#define FDIM  1024
#define NEXP  8

typedef __attribute__((ext_vector_type(8))) short bf16x8;
typedef __attribute__((ext_vector_type(4))) float f32x4;
typedef __attribute__((ext_vector_type(8))) unsigned short u16x8;

__device__ __forceinline__ unsigned short f2bf(float f) {
  unsigned int u = __float_as_uint(f);
  u += 0x7FFFu + ((u >> 16) & 1u);   // RNE
  return (unsigned short)(u >> 16);
}
__device__ __forceinline__ float bf2f(unsigned short u) {
  return __uint_as_float(((unsigned int)u) << 16);
}

__device__ __forceinline__ void gload_lds16(const void* g, void* l) {
  __builtin_amdgcn_global_load_lds(
      (const __attribute__((address_space(1))) unsigned int*)g,
      (__attribute__((address_space(3))) unsigned int*)l, 16, 0, 0);
}

// raw sync primitives (gemm2's counted pipeline)
__device__ __forceinline__ void vwait6() { asm volatile("s_waitcnt vmcnt(6)" ::: "memory"); }
__device__ __forceinline__ void vwait0() { asm volatile("s_waitcnt vmcnt(0)" ::: "memory"); }
__device__ __forceinline__ void lwait0() { asm volatile("s_waitcnt lgkmcnt(0)" ::: "memory"); }
__device__ __forceinline__ void barr()   { asm volatile("s_barrier" ::: "memory"); }

// swizzled fragment read: tile rows are 64 bf16 = 128B; byte ^= ((row&7)<<4)
// matches the pre-swizzled global source in the staging loops (rule #21).
__device__ __forceinline__ bf16x8 frag_ld(const unsigned short* tile, int row, int kk) {
  int byteoff = (row << 7) + ((kk * 2) ^ ((row & 7) << 4));
  return *reinterpret_cast<const bf16x8*>(reinterpret_cast<const char*>(tile) + byteoff);
}

// ---------------- prep: w1/w3 fp32->bf16 (blocks 0..2047) + gate (blocks 2048..3071) ----
// w2 conversion lives in gemm1's dispatch (rides in gemm1's HBM-BW shadow).
__global__ __launch_bounds__(256) void prep_kernel(
    const float* __restrict__ w1, const float* __restrict__ w3,
    unsigned short* __restrict__ W1b, unsigned short* __restrict__ W3b,
    const float* __restrict__ x, const float* __restrict__ gw,
    unsigned int* __restrict__ Xb32, int* __restrict__ tkidx, float* __restrict__ tkw,
    int* __restrict__ curp) {
  __shared__ float gws[NEXP * DDIM];   // 32 KB (gate blocks only)
  const int bid = blockIdx.x;
  const int tid = threadIdx.x;

  if (bid < 2048) {
    // ---- weight conversion: 1024 blocks per matrix (w1, w3) ----
    const int sub = bid >> 10;
    const int b = bid & 1023;
    const float* s = (sub == 0) ? w1 : w3;
    unsigned short* d = (sub == 0) ? W1b : W3b;
    const int n = NEXP * FDIM * DDIM;
    const int stride = 1024 * 256 * 8;
    for (int i = (b * 256 + tid) * 8; i < n; i += stride) {
      float4 a = *reinterpret_cast<const float4*>(s + i);
      float4 c = *reinterpret_cast<const float4*>(s + i + 4);
      u16x8 o;
      o[0] = f2bf(a.x); o[1] = f2bf(a.y); o[2] = f2bf(a.z); o[3] = f2bf(a.w);
      o[4] = f2bf(c.x); o[5] = f2bf(c.y); o[6] = f2bf(c.z); o[7] = f2bf(c.w);
      *reinterpret_cast<u16x8*>(d + i) = o;
    }
    return;
  }

  // ---- gate: 1024 blocks, 1 token per wave ----
  const int lane = tid & 63;
  const int wid = tid >> 6;
  if (bid == 2048 && tid < NEXP) curp[tid * 32] = 0;   // zero padded cursors for fill
  for (int i = tid; i < NEXP * DDIM / 4; i += 256)
    reinterpret_cast<float4*>(gws)[i] = reinterpret_cast<const float4*>(gw)[i];
  __syncthreads();

  const int t = (bid - 2048) * 4 + wid;
  const float2* xr = reinterpret_cast<const float2*>(x + (size_t)t * DDIM);
  float2 xv[8];
#pragma unroll
  for (int i = 0; i < 8; ++i) xv[i] = xr[i * 64 + lane];
  // fused x -> bf16 (packed pair store, coalesced 4B/lane)
#pragma unroll
  for (int i = 0; i < 8; ++i)
    Xb32[(size_t)t * 512 + i * 64 + lane] =
        (unsigned int)f2bf(xv[i].x) | ((unsigned int)f2bf(xv[i].y) << 16);
  float p[NEXP];
#pragma unroll
  for (int e = 0; e < NEXP; ++e) p[e] = 0.f;
#pragma unroll
  for (int i = 0; i < 8; ++i) {
    const int k = (i * 64 + lane) * 2;
#pragma unroll
    for (int e = 0; e < NEXP; ++e)
      p[e] += xv[i].x * gws[e * DDIM + k] + xv[i].y * gws[e * DDIM + k + 1];
  }
#pragma unroll
  for (int s = 32; s > 0; s >>= 1)
#pragma unroll
    for (int e = 0; e < NEXP; ++e) p[e] += __shfl_xor(p[e], s, 64);
  if (lane == 0) {
    int i0 = 0; float l0 = p[0];
#pragma unroll
    for (int e = 1; e < NEXP; ++e) if (p[e] > l0) { l0 = p[e]; i0 = e; }
    int i1 = -1; float l1 = -1e30f;
#pragma unroll
    for (int e = 0; e < NEXP; ++e) if (e != i0 && p[e] > l1) { l1 = p[e]; i1 = e; }
    float ex = __expf(l1 - l0);            // <= 1
    float w0 = 1.f / (1.f + ex);
    float w1v = ex / (1.f + ex);
    tkidx[t * 2] = i0; tkidx[t * 2 + 1] = i1;
    tkw[t * 2] = w0;   tkw[t * 2 + 1] = w1v;
  }
}

// ---------------- fill: global hist + off + compaction + compact work list ----------------
__global__ __launch_bounds__(256) void fill_kernel(const int* __restrict__ tkidx,
                                                   const float* __restrict__ tkw,
                                                   int* __restrict__ offp,
                                                   int* __restrict__ curp,
                                                   int* __restrict__ list,
                                                   float* __restrict__ rgate,
                                                   int* __restrict__ wmap,
                                                   int* __restrict__ nwp) {
  __shared__ int ghist[4][NEXP];
  __shared__ int lhist[NEXP], base[NEXP];
  const int tid = threadIdx.x;
  if (tid < 32) ghist[tid >> 3][tid & 7] = 0;
  if (tid < NEXP) lhist[tid] = 0;
  __syncthreads();
  for (int i = tid; i < 2 * T_TOK; i += 256)
    atomicAdd(&ghist[tid >> 6][tkidx[i]], 1);
  const int t = blockIdx.x * 256 + tid;
  const int e0 = tkidx[t * 2], e1 = tkidx[t * 2 + 1];
  const int r0 = atomicAdd(&lhist[e0], 1);
  const int r1 = atomicAdd(&lhist[e1], 1);
  __syncthreads();
  if (blockIdx.x == 0 && tid == 64) {
    // build compact (expert, rowtile) work list
    int nw = 0;
    for (int e = 0; e < NEXP; ++e) {
      int c = ghist[0][e] + ghist[1][e] + ghist[2][e] + ghist[3][e];
      int nrt = (c + 127) >> 7;
      for (int r = 0; r < nrt; ++r) wmap[nw++] = (e << 8) | r;
    }
    nwp[0] = nw;
  }
  if (tid < NEXP) {
    int o = 0;
#pragma unroll
    for (int j = 0; j < NEXP; ++j) {
      int c = ghist[0][j] + ghist[1][j] + ghist[2][j] + ghist[3][j];
      if (j < tid) o += c;
    }
    if (blockIdx.x == 0) {
      offp[tid] = o;
      if (tid == NEXP - 1)
        offp[NEXP] = o + ghist[0][tid] + ghist[1][tid] + ghist[2][tid] + ghist[3][tid];
    }
    base[tid] = o + atomicAdd(&curp[tid * 32], lhist[tid]);
  }
  __syncthreads();
  const int p0 = base[e0] + r0;
  const int p1 = base[e1] + r1;
  list[p0] = (t << 1);     rgate[p0] = tkw[t * 2];
  list[p1] = (t << 1) | 1; rgate[p1] = tkw[t * 2 + 1];
}

// ---------------- GEMM1: H = silu(X w1^T) * (X w3^T), gathered rows ----------------
// BM=128 tokens, BN=64 f-cols, BK=64. Single-buffered 32 KB LDS, 2-barrier loop,
// 84 VGPR -> 5 blocks/CU. This EXACT body measured 60.6us (round 2); four
// restructures (BK=32 pipeline, BN=32 pipeline, 128x128 fat tile, reg-staged B
// dbuf) all regressed 65-94us — the kernel is TLP-stall-hiding-limited, and
// every variant that cut occupancy or per-phase compute lost. Do not restructure
// without a within-probe A/B.
// Blocks >= 72*16 convert w2 fp32->bf16 (rides in gemm1's ~25%-HBM shadow).
__global__ __launch_bounds__(256) void gemm1_kernel(
    const unsigned short* __restrict__ Xb, const unsigned short* __restrict__ W1b,
    const unsigned short* __restrict__ W3b, unsigned short* __restrict__ Hb,
    const int* __restrict__ off, const int* __restrict__ list,
    const int* __restrict__ wmap, const int* __restrict__ nwp,
    const float* __restrict__ w2, unsigned short* __restrict__ W2b) {
  const int bid0 = blockIdx.x;
  const int tid = threadIdx.x;

  if (bid0 >= 72 * 16) {
    // ---- embedded w2 fp32->bf16 conversion (1024 blocks) ----
    const int b = bid0 - 72 * 16;
    const int n = NEXP * FDIM * DDIM;
    const int stride = 1024 * 256 * 8;
    for (int i = (b * 256 + tid) * 8; i < n; i += stride) {
      float4 a = *reinterpret_cast<const float4*>(w2 + i);
      float4 c = *reinterpret_cast<const float4*>(w2 + i + 4);
      u16x8 o;
      o[0] = f2bf(a.x); o[1] = f2bf(a.y); o[2] = f2bf(a.z); o[3] = f2bf(a.w);
      o[4] = f2bf(c.x); o[5] = f2bf(c.y); o[6] = f2bf(c.z); o[7] = f2bf(c.w);
      *reinterpret_cast<u16x8*>(W2b + i) = o;
    }
    return;
  }

  const int slot = bid0 >> 4;     // 72 rowtile slots
  const int ft = bid0 & 15;       // 16 f-col tiles of 64
  if (slot >= nwp[0]) return;
  const int ent = wmap[slot];
  const int e = ent >> 8;
  const int rt = ent & 255;
  const int seg0 = off[e];
  const int Ne = off[e + 1] - seg0;
  const int rowbase = rt * 128;   // < Ne by wmap construction
  const int f0 = ft * 64;

  __shared__ unsigned short As[128 * 64];   // 16 KB
  __shared__ unsigned short B1s[64 * 64];   //  8 KB
  __shared__ unsigned short B3s[64 * 64];   //  8 KB

  const int lane = tid & 63;
  const int wid = tid >> 6;
  const int wr = wid >> 1, wc = wid & 1;

  int ldsoffA[4]; size_t abase[4];
  int ldsoffB[2]; size_t b1base[2];
#pragma unroll
  for (int j = 0; j < 4; ++j) {
    int boff = j * 4096 + wid * 1024 + lane * 16;
    int row = boff >> 7;
    int c = ((boff >> 4) & 7) ^ (row & 7);
    ldsoffA[j] = (j * 4096 + wid * 1024) >> 1;
    int ar = rowbase + row; if (ar > Ne - 1) ar = Ne - 1;
    int tok = list[seg0 + ar] >> 1;
    abase[j] = (size_t)tok * DDIM + c * 8;
  }
#pragma unroll
  for (int j = 0; j < 2; ++j) {
    int boff = j * 4096 + wid * 1024 + lane * 16;
    int row = boff >> 7;
    int c = ((boff >> 4) & 7) ^ (row & 7);
    ldsoffB[j] = (j * 4096 + wid * 1024) >> 1;
    b1base[j] = (size_t)(e * FDIM + f0 + row) * DDIM + c * 8;
  }

  f32x4 acc1[4][2], acc3[4][2];
  const f32x4 z = {0.f, 0.f, 0.f, 0.f};
#pragma unroll
  for (int m = 0; m < 4; ++m)
#pragma unroll
    for (int n = 0; n < 2; ++n) { acc1[m][n] = z; acc3[m][n] = z; }

  const int lrow = lane & 15;
  const int kb = (lane >> 4) * 8;
  for (int kt = 0; kt < DDIM / 64; ++kt) {
    const int ko = kt * 64;
#pragma unroll
    for (int j = 0; j < 4; ++j)
      gload_lds16(Xb + abase[j] + ko, &As[ldsoffA[j]]);
#pragma unroll
    for (int j = 0; j < 2; ++j) {
      gload_lds16(W1b + b1base[j] + ko, &B1s[ldsoffB[j]]);
      gload_lds16(W3b + b1base[j] + ko, &B3s[ldsoffB[j]]);
    }
    __syncthreads();
#pragma unroll
    for (int ks = 0; ks < 2; ++ks) {
      bf16x8 a[4], p[2], q[2];
#pragma unroll
      for (int m = 0; m < 4; ++m)
        a[m] = frag_ld(As, wr * 64 + m * 16 + lrow, ks * 32 + kb);
#pragma unroll
      for (int n = 0; n < 2; ++n) {
        p[n] = frag_ld(B1s, wc * 32 + n * 16 + lrow, ks * 32 + kb);
        q[n] = frag_ld(B3s, wc * 32 + n * 16 + lrow, ks * 32 + kb);
      }
#pragma unroll
      for (int m = 0; m < 4; ++m)
#pragma unroll
        for (int n = 0; n < 2; ++n) {
          acc1[m][n] = __builtin_amdgcn_mfma_f32_16x16x32_bf16(a[m], p[n], acc1[m][n], 0, 0, 0);
          acc3[m][n] = __builtin_amdgcn_mfma_f32_16x16x32_bf16(a[m], q[n], acc3[m][n], 0, 0, 0);
        }
    }
    __syncthreads();
  }

  // epilogue: SiLU(h1)*h3 -> bf16 H (C/D layout: col=lane&15, row=(lane>>4)*4+r)
#pragma unroll
  for (int m = 0; m < 4; ++m)
#pragma unroll
    for (int n = 0; n < 2; ++n)
#pragma unroll
      for (int r = 0; r < 4; ++r) {
        int rloc = wr * 64 + m * 16 + ((lane >> 4) << 2) + r;
        if (rowbase + rloc < Ne) {
          float v1 = acc1[m][n][r], v3 = acc3[m][n][r];
          float h = v1 / (1.f + __expf(-v1)) * v3;
          int col = f0 + wc * 32 + n * 16 + (lane & 15);
          Hb[(size_t)(seg0 + rowbase + rloc) * FDIM + col] = f2bf(h);
        }
      }
}

// ---------------- GEMM2: Y[(t<<1)|k] = gate * (H w2^T), bf16 out, NO atomics ----------------
// BM=128, BN=64, BK=64. Depth-2 counted-vmcnt pipeline, 6 gloads/wave/tile, 48 KB LDS.
__global__ __launch_bounds__(256) void gemm2_kernel(
    const unsigned short* __restrict__ Hb, const unsigned short* __restrict__ W2b,
    unsigned short* __restrict__ Yb, const int* __restrict__ off,
    const int* __restrict__ list, const float* __restrict__ rgate,
    const int* __restrict__ wmap, const int* __restrict__ nwp) {
  const int bid0 = blockIdx.x;
  const int slot = bid0 >> 4;     // 72 rowtile slots
  const int dt = bid0 & 15;       // 16 d-col tiles
  if (slot >= nwp[0]) return;
  const int ent = wmap[slot];
  const int e = ent >> 8;
  const int rt = ent & 255;
  const int seg0 = off[e];
  const int Ne = off[e + 1] - seg0;
  const int rowbase = rt * 128;
  const int d0 = dt * 64;

  __shared__ unsigned short As[2][128 * 64];   // 32 KB
  __shared__ unsigned short Bs[2][64 * 64];    // 16 KB

  const int tid = threadIdx.x;
  const int lane = tid & 63;
  const int wid = tid >> 6;
  const int wr = wid >> 1, wc = wid & 1;

  int ldsoffA[4]; size_t abase[4];
  int ldsoffB[2]; size_t bbase[2];
#pragma unroll
  for (int j = 0; j < 4; ++j) {
    int boff = j * 4096 + wid * 1024 + lane * 16;
    int row = boff >> 7;
    int c = ((boff >> 4) & 7) ^ (row & 7);
    ldsoffA[j] = (j * 4096 + wid * 1024) >> 1;
    int ar = rowbase + row; if (ar > Ne - 1) ar = Ne - 1;
    abase[j] = (size_t)(seg0 + ar) * FDIM + c * 8;
  }
#pragma unroll
  for (int j = 0; j < 2; ++j) {
    int boff = j * 4096 + wid * 1024 + lane * 16;
    int row = boff >> 7;
    int c = ((boff >> 4) & 7) ^ (row & 7);
    ldsoffB[j] = (j * 4096 + wid * 1024) >> 1;
    bbase[j] = (size_t)(e * DDIM + d0 + row) * FDIM + c * 8;
  }

  f32x4 acc[4][2];
  const f32x4 z = {0.f, 0.f, 0.f, 0.f};
#pragma unroll
  for (int m = 0; m < 4; ++m)
#pragma unroll
    for (int n = 0; n < 2; ++n) acc[m][n] = z;

  auto stage = [&](int buf, int kt) {
    const int ko = kt * 64;
#pragma unroll
    for (int j = 0; j < 4; ++j)
      gload_lds16(Hb + abase[j] + ko, &As[buf][ldsoffA[j]]);
#pragma unroll
    for (int j = 0; j < 2; ++j)
      gload_lds16(W2b + bbase[j] + ko, &Bs[buf][ldsoffB[j]]);
  };

  const int lrow = lane & 15;
  const int kb = (lane >> 4) * 8;

  vwait0();
  stage(0, 0);              // 6 in flight
  stage(1, 1);              // 12 in flight
  vwait6();
  barr();

  for (int t = 0; t < 16; ++t) {
    const int b = t & 1;
#pragma unroll
    for (int ks = 0; ks < 2; ++ks) {
      bf16x8 a[4], bb[2];
#pragma unroll
      for (int m = 0; m < 4; ++m)
        a[m] = frag_ld(As[b], wr * 64 + m * 16 + lrow, ks * 32 + kb);
#pragma unroll
      for (int n = 0; n < 2; ++n)
        bb[n] = frag_ld(Bs[b], wc * 32 + n * 16 + lrow, ks * 32 + kb);
#pragma unroll
      for (int m = 0; m < 4; ++m)
#pragma unroll
        for (int n = 0; n < 2; ++n)
          acc[m][n] = __builtin_amdgcn_mfma_f32_16x16x32_bf16(a[m], bb[n], acc[m][n], 0, 0, 0);
    }
    if (t == 15) break;
    lwait0();
    barr();
    if (t + 2 < 16) stage(b, t + 2);
    if (t < 14) vwait6(); else vwait0();
    barr();
  }

  // epilogue: scale by gate, store bf16 into Y[(t<<1)|k] (rg <-> (t,k) bijective)
#pragma unroll
  for (int m = 0; m < 4; ++m)
#pragma unroll
    for (int r = 0; r < 4; ++r) {
      int rloc = wr * 64 + m * 16 + ((lane >> 4) << 2) + r;
      if (rowbase + rloc < Ne) {
        int rg = seg0 + rowbase + rloc;
        int tk = list[rg];
        float gsc = rgate[rg];
#pragma unroll
        for (int n = 0; n < 2; ++n) {
          int col = d0 + wc * 32 + n * 16 + (lane & 15);
          Yb[(size_t)tk * DDIM + col] = f2bf(gsc * acc[m][n][r]);
        }
      }
    }
}

// ---------------- combine: out[t] = Y[2t] + Y[2t+1]  (bf16 in, fp32 out) ----------------
__global__ __launch_bounds__(256) void combine_kernel(const unsigned short* __restrict__ Yb,
                                                      float* __restrict__ out) {
  const int n = T_TOK * DDIM / 8;   // groups of 8 elements
  const int stride = gridDim.x * blockDim.x;
  for (int i = blockIdx.x * blockDim.x + threadIdx.x; i < n; i += stride) {
    int t = i >> 7;                 // 128 groups per token row
    int c = (i & 127) * 8;
    u16x8 a = *reinterpret_cast<const u16x8*>(Yb + ((size_t)t * 2) * DDIM + c);
    u16x8 b = *reinterpret_cast<const u16x8*>(Yb + ((size_t)t * 2 + 1) * DDIM + c);
    float4 o0, o1;
    o0.x = bf2f(a[0]) + bf2f(b[0]); o0.y = bf2f(a[1]) + bf2f(b[1]);
    o0.z = bf2f(a[2]) + bf2f(b[2]); o0.w = bf2f(a[3]) + bf2f(b[3]);
    o1.x = bf2f(a[4]) + bf2f(b[4]); o1.y = bf2f(a[5]) + bf2f(b[5]);
    o1.z = bf2f(a[6]) + bf2f(b[6]); o1.w = bf2f(a[7]) + bf2f(b[7]);
    float* dst = out + (size_t)t * DDIM + c;
    *reinterpret_cast<float4*>(dst) = o0;
    *reinterpret_cast<float4*>(dst + 4) = o1;
  }
}

extern "C" void kernel_launch(void* const* d_in, const int* in_sizes, int n_in,
                              void* d_out, int out_size, void* d_ws, size_t ws_size,
                              hipStream_t stream) {
  (void)in_sizes; (void)n_in; (void)ws_size; (void)out_size;
  const float* x  = (const float*)d_in[0];
  const float* gw = (const float*)d_in[1];
  const float* w1 = (const float*)d_in[2];
  const float* w3 = (const float*)d_in[3];
  const float* w2 = (const float*)d_in[4];
  float* out = (float*)d_out;

  char* ws = (char*)d_ws;
  unsigned short* Xb  = (unsigned short*)(ws + 0);            //  8 MB
  unsigned short* W1b = (unsigned short*)(ws + 8388608);      // 16 MB
  unsigned short* W3b = (unsigned short*)(ws + 25165824);     // 16 MB
  unsigned short* W2b = (unsigned short*)(ws + 41943040);     // 16 MB
  unsigned short* Hb  = (unsigned short*)(ws + 58720256);     // 16 MB
  // Yb (16.8 MB bf16) overlays W1b — dead once gemm1 finishes.
  unsigned short* Yb  = (unsigned short*)(ws + 8388608);
  int*   ctrl  = (int*)(ws + 75497472);
  int*   off   = ctrl;           // off[0..8] (written by fill block 0)
  int*   nwp   = ctrl + 12;      // work-list count
  int*   curp  = ctrl + 16;      // curp[e*32], 128B-padded (zeroed in prep)
  int*   wmap  = ctrl + 256;     // <=72 packed (e<<8|rowtile) entries
  int*   tkidx = (int*)(ws + 75497472 + 4096);
  float* tkw   = (float*)(ws + 75497472 + 4096 + 32768);
  int*   list  = (int*)(ws + 75497472 + 4096 + 65536);
  float* rgate = (float*)(ws + 75497472 + 4096 + 98304);

  prep_kernel<<<3072, 256, 0, stream>>>(w1, w3, W1b, W3b,
                                        x, gw, (unsigned int*)Xb, tkidx, tkw, curp);
  fill_kernel<<<16, 256, 0, stream>>>(tkidx, tkw, off, curp, list, rgate, wmap, nwp);

  gemm1_kernel<<<72 * 16 + 1024, 256, 0, stream>>>(Xb, W1b, W3b, Hb, off, list,
                                                   wmap, nwp, w2, W2b);
  gemm2_kernel<<<72 * 16, 256, 0, stream>>>(Hb, W2b, Yb, off, list, rgate, wmap, nwp);
  combine_kernel<<<2048, 256, 0, stream>>>(Yb, out);
}

// Round 7
// 131.542 us; speedup vs baseline: 1.2639x; 1.0135x over previous
//
#include <hip/hip_runtime.h>
#include <hip/hip_bf16.h>
#include <cstdint>
#include <cstddef>

// Problem constants (B,S,D,F,E,K) = (2,2048,1024,1024,8,2)
#define T_TOK 4096
#define DDIM  1024
#define FDIM  1024
#define NEXP  8

typedef __attribute__((ext_vector_type(8))) short bf16x8;
typedef __attribute__((ext_vector_type(4))) float f32x4;
typedef __attribute__((ext_vector_type(8))) unsigned short u16x8;

__device__ __forceinline__ unsigned short f2bf(float f) {
  unsigned int u = __float_as_uint(f);
  u += 0x7FFFu + ((u >> 16) & 1u);   // RNE
  return (unsigned short)(u >> 16);
}
__device__ __forceinline__ float bf2f(unsigned short u) {
  return __uint_as_float(((unsigned int)u) << 16);
}

__device__ __forceinline__ void gload_lds16(const void* g, void* l) {
  __builtin_amdgcn_global_load_lds(
      (const __attribute__((address_space(1))) unsigned int*)g,
      (__attribute__((address_space(3))) unsigned int*)l, 16, 0, 0);
}

// raw sync primitives (gemm2's counted pipeline)
__device__ __forceinline__ void vwait6() { asm volatile("s_waitcnt vmcnt(6)" ::: "memory"); }
__device__ __forceinline__ void vwait0() { asm volatile("s_waitcnt vmcnt(0)" ::: "memory"); }
__device__ __forceinline__ void lwait0() { asm volatile("s_waitcnt lgkmcnt(0)" ::: "memory"); }
__device__ __forceinline__ void barr()   { asm volatile("s_barrier" ::: "memory"); }

// swizzled fragment read: tile rows are 64 bf16 = 128B; byte ^= ((row&7)<<4)
// matches the pre-swizzled global source in the staging loops (rule #21).
__device__ __forceinline__ bf16x8 frag_ld(const unsigned short* tile, int row, int kk) {
  int byteoff = (row << 7) + ((kk * 2) ^ ((row & 7) << 4));
  return *reinterpret_cast<const bf16x8*>(reinterpret_cast<const char*>(tile) + byteoff);
}

// ---------------- prep: w1/w3 fp32->bf16 (blocks 0..2047) + gate (blocks 2048..3071) ----
// w2 conversion lives in gemm1's dispatch (rides in gemm1's HBM-BW shadow).
__global__ __launch_bounds__(256) void prep_kernel(
    const float* __restrict__ w1, const float* __restrict__ w3,
    unsigned short* __restrict__ W1b, unsigned short* __restrict__ W3b,
    const float* __restrict__ x, const float* __restrict__ gw,
    unsigned int* __restrict__ Xb32, int* __restrict__ tkidx, float* __restrict__ tkw,
    int* __restrict__ curp) {
  __shared__ float gws[NEXP * DDIM];   // 32 KB (gate blocks only)
  const int bid = blockIdx.x;
  const int tid = threadIdx.x;

  if (bid < 2048) {
    // ---- weight conversion: 1024 blocks per matrix (w1, w3) ----
    const int sub = bid >> 10;
    const int b = bid & 1023;
    const float* s = (sub == 0) ? w1 : w3;
    unsigned short* d = (sub == 0) ? W1b : W3b;
    const int n = NEXP * FDIM * DDIM;
    const int stride = 1024 * 256 * 8;
    for (int i = (b * 256 + tid) * 8; i < n; i += stride) {
      float4 a = *reinterpret_cast<const float4*>(s + i);
      float4 c = *reinterpret_cast<const float4*>(s + i + 4);
      u16x8 o;
      o[0] = f2bf(a.x); o[1] = f2bf(a.y); o[2] = f2bf(a.z); o[3] = f2bf(a.w);
      o[4] = f2bf(c.x); o[5] = f2bf(c.y); o[6] = f2bf(c.z); o[7] = f2bf(c.w);
      *reinterpret_cast<u16x8*>(d + i) = o;
    }
    return;
  }

  // ---- gate: 1024 blocks, 1 token per wave ----
  const int lane = tid & 63;
  const int wid = tid >> 6;
  if (bid == 2048 && tid < NEXP) curp[tid * 32] = 0;   // zero padded cursors for fill
  for (int i = tid; i < NEXP * DDIM / 4; i += 256)
    reinterpret_cast<float4*>(gws)[i] = reinterpret_cast<const float4*>(gw)[i];
  __syncthreads();

  const int t = (bid - 2048) * 4 + wid;
  const float2* xr = reinterpret_cast<const float2*>(x + (size_t)t * DDIM);
  float2 xv[8];
#pragma unroll
  for (int i = 0; i < 8; ++i) xv[i] = xr[i * 64 + lane];
  // fused x -> bf16 (packed pair store, coalesced 4B/lane)
#pragma unroll
  for (int i = 0; i < 8; ++i)
    Xb32[(size_t)t * 512 + i * 64 + lane] =
        (unsigned int)f2bf(xv[i].x) | ((unsigned int)f2bf(xv[i].y) << 16);
  float p[NEXP];
#pragma unroll
  for (int e = 0; e < NEXP; ++e) p[e] = 0.f;
#pragma unroll
  for (int i = 0; i < 8; ++i) {
    const int k = (i * 64 + lane) * 2;
#pragma unroll
    for (int e = 0; e < NEXP; ++e)
      p[e] += xv[i].x * gws[e * DDIM + k] + xv[i].y * gws[e * DDIM + k + 1];
  }
#pragma unroll
  for (int s = 32; s > 0; s >>= 1)
#pragma unroll
    for (int e = 0; e < NEXP; ++e) p[e] += __shfl_xor(p[e], s, 64);
  if (lane == 0) {
    int i0 = 0; float l0 = p[0];
#pragma unroll
    for (int e = 1; e < NEXP; ++e) if (p[e] > l0) { l0 = p[e]; i0 = e; }
    int i1 = -1; float l1 = -1e30f;
#pragma unroll
    for (int e = 0; e < NEXP; ++e) if (e != i0 && p[e] > l1) { l1 = p[e]; i1 = e; }
    float ex = __expf(l1 - l0);            // <= 1
    float w0 = 1.f / (1.f + ex);
    float w1v = ex / (1.f + ex);
    tkidx[t * 2] = i0; tkidx[t * 2 + 1] = i1;
    tkw[t * 2] = w0;   tkw[t * 2 + 1] = w1v;
  }
}

// ---------------- fill: global hist + off + compaction + compact work list ----------------
__global__ __launch_bounds__(256) void fill_kernel(const int* __restrict__ tkidx,
                                                   const float* __restrict__ tkw,
                                                   int* __restrict__ offp,
                                                   int* __restrict__ curp,
                                                   int* __restrict__ list,
                                                   float* __restrict__ rgate,
                                                   int* __restrict__ wmap,
                                                   int* __restrict__ nwp) {
  __shared__ int ghist[4][NEXP];
  __shared__ int lhist[NEXP], base[NEXP];
  const int tid = threadIdx.x;
  if (tid < 32) ghist[tid >> 3][tid & 7] = 0;
  if (tid < NEXP) lhist[tid] = 0;
  __syncthreads();
  for (int i = tid; i < 2 * T_TOK; i += 256)
    atomicAdd(&ghist[tid >> 6][tkidx[i]], 1);
  const int t = blockIdx.x * 256 + tid;
  const int e0 = tkidx[t * 2], e1 = tkidx[t * 2 + 1];
  const int r0 = atomicAdd(&lhist[e0], 1);
  const int r1 = atomicAdd(&lhist[e1], 1);
  __syncthreads();
  if (blockIdx.x == 0 && tid == 64) {
    // build compact (expert, rowtile) work list
    int nw = 0;
    for (int e = 0; e < NEXP; ++e) {
      int c = ghist[0][e] + ghist[1][e] + ghist[2][e] + ghist[3][e];
      int nrt = (c + 127) >> 7;
      for (int r = 0; r < nrt; ++r) wmap[nw++] = (e << 8) | r;
    }
    nwp[0] = nw;
  }
  if (tid < NEXP) {
    int o = 0;
#pragma unroll
    for (int j = 0; j < NEXP; ++j) {
      int c = ghist[0][j] + ghist[1][j] + ghist[2][j] + ghist[3][j];
      if (j < tid) o += c;
    }
    if (blockIdx.x == 0) {
      offp[tid] = o;
      if (tid == NEXP - 1)
        offp[NEXP] = o + ghist[0][tid] + ghist[1][tid] + ghist[2][tid] + ghist[3][tid];
    }
    base[tid] = o + atomicAdd(&curp[tid * 32], lhist[tid]);
  }
  __syncthreads();
  const int p0 = base[e0] + r0;
  const int p1 = base[e1] + r1;
  list[p0] = (t << 1);     rgate[p0] = tkw[t * 2];
  list[p1] = (t << 1) | 1; rgate[p1] = tkw[t * 2 + 1];
}

// ---------------- GEMM1: H = silu(X w1^T) * (X w3^T), gathered rows ----------------
// BM=128 tokens, BN=64 f-cols, BK=64. Single-buffered 32 KB LDS, 2-barrier loop,
// 84 VGPR -> 5 blocks/CU. This EXACT body measured 59.4-60.6us (rounds 2/6); four
// restructures (BK=32 pipeline, BN=32 pipeline, 128x128 fat tile, reg-staged B
// dbuf) all regressed 65-94us — the kernel is TLP-stall-hiding-limited. Do not
// restructure without a within-probe A/B.
// NEW (T1): XCD-chunked block swizzle. 1152 gemm blocks = 8 XCDs x 144; the remap
// logical=(bid%8)*144+bid/8 gives each XCD 9 contiguous slots (~one expert's
// 4MB B-panels + its A-panels) -> A/B L2 hits instead of 8x cross-XCD refetch.
// Blocks >= 72*16 convert w2 fp32->bf16 (rides in gemm1's ~25%-HBM shadow).
__global__ __launch_bounds__(256) void gemm1_kernel(
    const unsigned short* __restrict__ Xb, const unsigned short* __restrict__ W1b,
    const unsigned short* __restrict__ W3b, unsigned short* __restrict__ Hb,
    const int* __restrict__ off, const int* __restrict__ list,
    const int* __restrict__ wmap, const int* __restrict__ nwp,
    const float* __restrict__ w2, unsigned short* __restrict__ W2b) {
  const int bid0 = blockIdx.x;
  const int tid = threadIdx.x;

  if (bid0 >= 72 * 16) {
    // ---- embedded w2 fp32->bf16 conversion (1024 blocks) ----
    const int b = bid0 - 72 * 16;
    const int n = NEXP * FDIM * DDIM;
    const int stride = 1024 * 256 * 8;
    for (int i = (b * 256 + tid) * 8; i < n; i += stride) {
      float4 a = *reinterpret_cast<const float4*>(w2 + i);
      float4 c = *reinterpret_cast<const float4*>(w2 + i + 4);
      u16x8 o;
      o[0] = f2bf(a.x); o[1] = f2bf(a.y); o[2] = f2bf(a.z); o[3] = f2bf(a.w);
      o[4] = f2bf(c.x); o[5] = f2bf(c.y); o[6] = f2bf(c.z); o[7] = f2bf(c.w);
      *reinterpret_cast<u16x8*>(W2b + i) = o;
    }
    return;
  }

  // XCD-chunked bijective remap: 1152 = 8 * 144 exactly
  const int g = (bid0 & 7) * 144 + (bid0 >> 3);
  const int slot = g >> 4;        // 72 rowtile slots
  const int ft = g & 15;          // 16 f-col tiles of 64
  if (slot >= nwp[0]) return;
  const int ent = wmap[slot];
  const int e = ent >> 8;
  const int rt = ent & 255;
  const int seg0 = off[e];
  const int Ne = off[e + 1] - seg0;
  const int rowbase = rt * 128;   // < Ne by wmap construction
  const int f0 = ft * 64;

  __shared__ unsigned short As[128 * 64];   // 16 KB
  __shared__ unsigned short B1s[64 * 64];   //  8 KB
  __shared__ unsigned short B3s[64 * 64];   //  8 KB

  const int lane = tid & 63;
  const int wid = tid >> 6;
  const int wr = wid >> 1, wc = wid & 1;

  int ldsoffA[4]; size_t abase[4];
  int ldsoffB[2]; size_t b1base[2];
#pragma unroll
  for (int j = 0; j < 4; ++j) {
    int boff = j * 4096 + wid * 1024 + lane * 16;
    int row = boff >> 7;
    int c = ((boff >> 4) & 7) ^ (row & 7);
    ldsoffA[j] = (j * 4096 + wid * 1024) >> 1;
    int ar = rowbase + row; if (ar > Ne - 1) ar = Ne - 1;
    int tok = list[seg0 + ar] >> 1;
    abase[j] = (size_t)tok * DDIM + c * 8;
  }
#pragma unroll
  for (int j = 0; j < 2; ++j) {
    int boff = j * 4096 + wid * 1024 + lane * 16;
    int row = boff >> 7;
    int c = ((boff >> 4) & 7) ^ (row & 7);
    ldsoffB[j] = (j * 4096 + wid * 1024) >> 1;
    b1base[j] = (size_t)(e * FDIM + f0 + row) * DDIM + c * 8;
  }

  f32x4 acc1[4][2], acc3[4][2];
  const f32x4 z = {0.f, 0.f, 0.f, 0.f};
#pragma unroll
  for (int m = 0; m < 4; ++m)
#pragma unroll
    for (int n = 0; n < 2; ++n) { acc1[m][n] = z; acc3[m][n] = z; }

  const int lrow = lane & 15;
  const int kb = (lane >> 4) * 8;
  for (int kt = 0; kt < DDIM / 64; ++kt) {
    const int ko = kt * 64;
#pragma unroll
    for (int j = 0; j < 4; ++j)
      gload_lds16(Xb + abase[j] + ko, &As[ldsoffA[j]]);
#pragma unroll
    for (int j = 0; j < 2; ++j) {
      gload_lds16(W1b + b1base[j] + ko, &B1s[ldsoffB[j]]);
      gload_lds16(W3b + b1base[j] + ko, &B3s[ldsoffB[j]]);
    }
    __syncthreads();
#pragma unroll
    for (int ks = 0; ks < 2; ++ks) {
      bf16x8 a[4], p[2], q[2];
#pragma unroll
      for (int m = 0; m < 4; ++m)
        a[m] = frag_ld(As, wr * 64 + m * 16 + lrow, ks * 32 + kb);
#pragma unroll
      for (int n = 0; n < 2; ++n) {
        p[n] = frag_ld(B1s, wc * 32 + n * 16 + lrow, ks * 32 + kb);
        q[n] = frag_ld(B3s, wc * 32 + n * 16 + lrow, ks * 32 + kb);
      }
#pragma unroll
      for (int m = 0; m < 4; ++m)
#pragma unroll
        for (int n = 0; n < 2; ++n) {
          acc1[m][n] = __builtin_amdgcn_mfma_f32_16x16x32_bf16(a[m], p[n], acc1[m][n], 0, 0, 0);
          acc3[m][n] = __builtin_amdgcn_mfma_f32_16x16x32_bf16(a[m], q[n], acc3[m][n], 0, 0, 0);
        }
    }
    __syncthreads();
  }

  // epilogue: SiLU(h1)*h3 -> bf16 H (C/D layout: col=lane&15, row=(lane>>4)*4+r)
#pragma unroll
  for (int m = 0; m < 4; ++m)
#pragma unroll
    for (int n = 0; n < 2; ++n)
#pragma unroll
      for (int r = 0; r < 4; ++r) {
        int rloc = wr * 64 + m * 16 + ((lane >> 4) << 2) + r;
        if (rowbase + rloc < Ne) {
          float v1 = acc1[m][n][r], v3 = acc3[m][n][r];
          float h = v1 / (1.f + __expf(-v1)) * v3;
          int col = f0 + wc * 32 + n * 16 + (lane & 15);
          Hb[(size_t)(seg0 + rowbase + rloc) * FDIM + col] = f2bf(h);
        }
      }
}

// ---------------- GEMM2: Y[(t<<1)|k] = gate * (H w2^T), bf16 out, NO atomics ----------------
// BM=128, BN=64, BK=64. Depth-2 counted-vmcnt pipeline, 6 gloads/wave/tile, 48 KB LDS.
// Same T1 XCD-chunked remap (1152 = 8 x 144).
__global__ __launch_bounds__(256) void gemm2_kernel(
    const unsigned short* __restrict__ Hb, const unsigned short* __restrict__ W2b,
    unsigned short* __restrict__ Yb, const int* __restrict__ off,
    const int* __restrict__ list, const float* __restrict__ rgate,
    const int* __restrict__ wmap, const int* __restrict__ nwp) {
  const int bid0 = blockIdx.x;
  const int g = (bid0 & 7) * 144 + (bid0 >> 3);
  const int slot = g >> 4;        // 72 rowtile slots
  const int dt = g & 15;          // 16 d-col tiles
  if (slot >= nwp[0]) return;
  const int ent = wmap[slot];
  const int e = ent >> 8;
  const int rt = ent & 255;
  const int seg0 = off[e];
  const int Ne = off[e + 1] - seg0;
  const int rowbase = rt * 128;
  const int d0 = dt * 64;

  __shared__ unsigned short As[2][128 * 64];   // 32 KB
  __shared__ unsigned short Bs[2][64 * 64];    // 16 KB

  const int tid = threadIdx.x;
  const int lane = tid & 63;
  const int wid = tid >> 6;
  const int wr = wid >> 1, wc = wid & 1;

  int ldsoffA[4]; size_t abase[4];
  int ldsoffB[2]; size_t bbase[2];
#pragma unroll
  for (int j = 0; j < 4; ++j) {
    int boff = j * 4096 + wid * 1024 + lane * 16;
    int row = boff >> 7;
    int c = ((boff >> 4) & 7) ^ (row & 7);
    ldsoffA[j] = (j * 4096 + wid * 1024) >> 1;
    int ar = rowbase + row; if (ar > Ne - 1) ar = Ne - 1;
    abase[j] = (size_t)(seg0 + ar) * FDIM + c * 8;
  }
#pragma unroll
  for (int j = 0; j < 2; ++j) {
    int boff = j * 4096 + wid * 1024 + lane * 16;
    int row = boff >> 7;
    int c = ((boff >> 4) & 7) ^ (row & 7);
    ldsoffB[j] = (j * 4096 + wid * 1024) >> 1;
    bbase[j] = (size_t)(e * DDIM + d0 + row) * FDIM + c * 8;
  }

  f32x4 acc[4][2];
  const f32x4 z = {0.f, 0.f, 0.f, 0.f};
#pragma unroll
  for (int m = 0; m < 4; ++m)
#pragma unroll
    for (int n = 0; n < 2; ++n) acc[m][n] = z;

  auto stage = [&](int buf, int kt) {
    const int ko = kt * 64;
#pragma unroll
    for (int j = 0; j < 4; ++j)
      gload_lds16(Hb + abase[j] + ko, &As[buf][ldsoffA[j]]);
#pragma unroll
    for (int j = 0; j < 2; ++j)
      gload_lds16(W2b + bbase[j] + ko, &Bs[buf][ldsoffB[j]]);
  };

  const int lrow = lane & 15;
  const int kb = (lane >> 4) * 8;

  vwait0();
  stage(0, 0);              // 6 in flight
  stage(1, 1);              // 12 in flight
  vwait6();
  barr();

  for (int t = 0; t < 16; ++t) {
    const int b = t & 1;
#pragma unroll
    for (int ks = 0; ks < 2; ++ks) {
      bf16x8 a[4], bb[2];
#pragma unroll
      for (int m = 0; m < 4; ++m)
        a[m] = frag_ld(As[b], wr * 64 + m * 16 + lrow, ks * 32 + kb);
#pragma unroll
      for (int n = 0; n < 2; ++n)
        bb[n] = frag_ld(Bs[b], wc * 32 + n * 16 + lrow, ks * 32 + kb);
#pragma unroll
      for (int m = 0; m < 4; ++m)
#pragma unroll
        for (int n = 0; n < 2; ++n)
          acc[m][n] = __builtin_amdgcn_mfma_f32_16x16x32_bf16(a[m], bb[n], acc[m][n], 0, 0, 0);
    }
    if (t == 15) break;
    lwait0();
    barr();
    if (t + 2 < 16) stage(b, t + 2);
    if (t < 14) vwait6(); else vwait0();
    barr();
  }

  // epilogue: scale by gate, store bf16 into Y[(t<<1)|k] (rg <-> (t,k) bijective)
#pragma unroll
  for (int m = 0; m < 4; ++m)
#pragma unroll
    for (int r = 0; r < 4; ++r) {
      int rloc = wr * 64 + m * 16 + ((lane >> 4) << 2) + r;
      if (rowbase + rloc < Ne) {
        int rg = seg0 + rowbase + rloc;
        int tk = list[rg];
        float gsc = rgate[rg];
#pragma unroll
        for (int n = 0; n < 2; ++n) {
          int col = d0 + wc * 32 + n * 16 + (lane & 15);
          Yb[(size_t)tk * DDIM + col] = f2bf(gsc * acc[m][n][r]);
        }
      }
    }
}

// ---------------- combine: out[t] = Y[2t] + Y[2t+1]  (bf16 in, fp32 out) ----------------
__global__ __launch_bounds__(256) void combine_kernel(const unsigned short* __restrict__ Yb,
                                                      float* __restrict__ out) {
  const int n = T_TOK * DDIM / 8;   // groups of 8 elements
  const int stride = gridDim.x * blockDim.x;
  for (int i = blockIdx.x * blockDim.x + threadIdx.x; i < n; i += stride) {
    int t = i >> 7;                 // 128 groups per token row
    int c = (i & 127) * 8;
    u16x8 a = *reinterpret_cast<const u16x8*>(Yb + ((size_t)t * 2) * DDIM + c);
    u16x8 b = *reinterpret_cast<const u16x8*>(Yb + ((size_t)t * 2 + 1) * DDIM + c);
    float4 o0, o1;
    o0.x = bf2f(a[0]) + bf2f(b[0]); o0.y = bf2f(a[1]) + bf2f(b[1]);
    o0.z = bf2f(a[2]) + bf2f(b[2]); o0.w = bf2f(a[3]) + bf2f(b[3]);
    o1.x = bf2f(a[4]) + bf2f(b[4]); o1.y = bf2f(a[5]) + bf2f(b[5]);
    o1.z = bf2f(a[6]) + bf2f(b[6]); o1.w = bf2f(a[7]) + bf2f(b[7]);
    float* dst = out + (size_t)t * DDIM + c;
    *reinterpret_cast<float4*>(dst) = o0;
    *reinterpret_cast<float4*>(dst + 4) = o1;
  }
}

extern "C" void kernel_launch(void* const* d_in, const int* in_sizes, int n_in,
                              void* d_out, int out_size, void* d_ws, size_t ws_size,
                              hipStream_t stream) {
  (void)in_sizes; (void)n_in; (void)ws_size; (void)out_size;
  const float* x  = (const float*)d_in[0];
  const float* gw = (const float*)d_in[1];
  const float* w1 = (const float*)d_in[2];
  const float* w3 = (const float*)d_in[3];
  const float* w2 = (const float*)d_in[4];
  float* out = (float*)d_out;

  char* ws = (char*)d_ws;
  unsigned short* Xb  = (unsigned short*)(ws + 0);            //  8 MB
  unsigned short* W1b = (unsigned short*)(ws + 8388608);      // 16 MB
  unsigned short* W3b = (unsigned short*)(ws + 25165824);     // 16 MB
  unsigned short* W2b = (unsigned short*)(ws + 41943040);     // 16 MB
  unsigned short* Hb  = (unsigned short*)(ws + 58720256);     // 16 MB
  // Yb (16.8 MB bf16) overlays W1b — dead once gemm1 finishes.
  unsigned short* Yb  = (unsigned short*)(ws + 8388608);
  int*   ctrl  = (int*)(ws + 75497472);
  int*   off   = ctrl;           // off[0..8] (written by fill block 0)
  int*   nwp   = ctrl + 12;      // work-list count
  int*   curp  = ctrl + 16;      // curp[e*32], 128B-padded (zeroed in prep)
  int*   wmap  = ctrl + 256;     // <=72 packed (e<<8|rowtile) entries
  int*   tkidx = (int*)(ws + 75497472 + 4096);
  float* tkw   = (float*)(ws + 75497472 + 4096 + 32768);
  int*   list  = (int*)(ws + 75497472 + 4096 + 65536);
  float* rgate = (float*)(ws + 75497472 + 4096 + 98304);

  prep_kernel<<<3072, 256, 0, stream>>>(w1, w3, W1b, W3b,
                                        x, gw, (unsigned int*)Xb, tkidx, tkw, curp);
  fill_kernel<<<16, 256, 0, stream>>>(tkidx, tkw, off, curp, list, rgate, wmap, nwp);

  gemm1_kernel<<<72 * 16 + 1024, 256, 0, stream>>>(Xb, W1b, W3b, Hb, off, list,
                                                   wmap, nwp, w2, W2b);
  gemm2_kernel<<<72 * 16, 256, 0, stream>>>(Hb, W2b, Yb, off, list, rgate, wmap, nwp);
  combine_kernel<<<2048, 256, 0, stream>>>(Yb, out);
}